// Round 5
// baseline (114954.480 us; speedup 1.0000x reference)
//
#include <hip/hip_runtime.h>
#include <math.h>

#define BB 64
#define TT 512
#define II 512
#define HH 512
#define PP 256
#define OO 512

#define NBLK 512
#define NTHR 512
#define RPB 4
#define AGT __HIP_MEMORY_SCOPE_AGENT

// ---- mutable fp64 state; all cross-block accesses via agent-scope (sc1) relaxed atomics ----
__device__ __align__(256) double g_h0d[2*BB*HH];   // double-buffered h_mem0 (by t&1)
__device__ __align__(256) double g_h1 [BB*HH];
__device__ __align__(256) double g_rh [2*BB*HH];   // per-layer
__device__ __align__(256) double g_hc [2*BB*HH];
__device__ __align__(256) double g_mo [2*BB*PP];
__device__ __align__(256) double g_hist[(long)BB*TT*HH];
__device__ unsigned g_sync[4096];                  // 32 groups x 4 stages, 128B apart

// ---- transposed weights (built by prep; per-XCD slices L2-resident, hot ones f64) ----
__device__ __align__(256) double g_WRUd [2L*1024*1024]; // [l][k][c*2+{r,u}] f64
__device__ __align__(256) float  g_WnT  [2*1024*512];   // [l][k][c] f32
__device__ __align__(256) float  g_WMG  [2*512*1024];   // [l][k][pc*4+{mw,mu,d,s}] f32
__device__ __align__(256) double g_WmrTd[2*512*256];    // [l][k][pc] f64
__device__ __align__(256) double g_WmhTd[2*256*512];    // [l][k][c] f64
__device__ __align__(256) double g_WoutTd[512*512];     // [k][c] f64

struct KP {
  const float *x,*Wr,*br,*Wu,*bu,*Wn,*bn,*Wmr,*bmr,*Wmw,*bmw,*Wmu,*bmu,
              *Wmh,*bmh,*Wd,*bd,*Ws,*bs,*Wout,*bout,*dop,*ser;
  float* out;
};

__device__ inline double sigd(double x){ return 1.0/(1.0+exp(-x)); }

// ---- prep: LDS-tiled transposes (both sides coalesced, f32->f64 where flagged) ----
__global__ void __launch_bounds__(256) prep(KP p)
{
  __shared__ float tile[32][33];
  const int b = blockIdx.x;
  const int T_RUN = 3072;          // Wr,Wu,Wn
  const int T_MG  = T_RUN + 1024;  // Wmw,Wmu,Wd,Ws
  const int T_MR  = T_MG  + 256;
  const int T_MH  = T_MR  + 256;
  const int T_OUT = T_MH  + 256;
  const int tid = threadIdx.x;

  const float* src=nullptr; void* dstv=nullptr;
  int K=0,C=0,st=1,off=0,k0=0,c0=0,dt=0;
  bool xpose=true;

  if (b < T_RUN){
    int m=b>>10, r=b&1023, l=r>>9, t=r&511;
    K=1024; C=512; int ct=t&15, kt=t>>4; k0=kt*32; c0=ct*32;
    src = (m==0? p.Wr : m==1? p.Wu : p.Wn) + (long)l*C*K;
    if (m<2){ dstv = g_WRUd + (long)l*1024*1024; st=2; off=m; dt=1; }
    else    { dstv = g_WnT  + (long)l*1024*512;  st=1; off=0; dt=0; }
  } else if (b < T_MG){
    int q=b-T_RUN, m=q>>8, r=q&255, l=r>>7, t=r&127;
    K=512; C=256; int ct=t&7, kt=t>>3; k0=kt*32; c0=ct*32;
    const float* s4[4]={p.Wmw,p.Wmu,p.Wd,p.Ws};
    src = s4[m] + (long)l*C*K;
    dstv = g_WMG + (long)l*512*1024; st=4; off=m; dt=0;
  } else if (b < T_MR){
    int r=b-T_MG, l=r>>7, t=r&127;
    K=512; C=256; int ct=t&7, kt=t>>3; k0=kt*32; c0=ct*32;
    src = p.Wmr + (long)l*C*K;
    dstv = g_WmrTd + (long)l*512*256; st=1; off=0; dt=1;
  } else if (b < T_MH){
    int r=b-T_MR, l=r>>7, t=r&127;
    K=256; C=512; int ct=t&15, kt=t>>4; k0=kt*32; c0=ct*32;
    src = p.Wmh + (long)l*C*K;
    dstv = g_WmhTd + (long)l*256*512; st=1; off=0; dt=1;
  } else if (b < T_OUT){
    int t=b-T_MH;
    K=512; C=512; int ct=t&15, kt=t>>4; k0=kt*32; c0=ct*32;
    src = p.Wout; dstv = g_WoutTd; st=1; off=0; dt=1;
  } else {
    xpose=false;
    long i = (long)(b-T_OUT)*256 + tid;
    if (i < 2L*BB*HH) g_h0d[i]=0.0;
    if (i < (long)BB*HH) g_h1[i]=0.0;
    if (i < 4096) g_sync[(int)i]=0u;
  }

  if (xpose){
    for (int i=tid;i<1024;i+=256){
      int ty=i>>5, tx=i&31;
      tile[ty][tx] = src[(long)(c0+ty)*K + k0+tx];
    }
    __syncthreads();
    for (int i=tid;i<1024;i+=256){
      int ky=i>>5, cx=i&31;
      long o = (long)(k0+ky)*C*st + (long)(c0+cx)*st + off;
      if (dt) ((double*)dstv)[o] = (double)tile[cx][ky];
      else    ((float*)dstv)[o]  = tile[cx][ky];
    }
  }
}

// ---- main: 2-layer pipeline, 4-row blocks, 2 blocks/CU, 16-block group barriers ----
__global__ void __launch_bounds__(NTHR,4) rnn_kernel(KP p)
{
  const int tid=threadIdx.x;
  const int xcd=blockIdx.x&7, lay=xcd>>2, xl=xcd&3;
  const int cs=(blockIdx.x>>3)&3, rb=blockIdx.x>>5;   // rb 0..15
  const int iw=tid>>6, row=iw>>1, ch=iw&1, lane=tid&63;
  const int r0g=rb*RPB;
  const int colH0=xl*128+cs*32, colP0=xl*64+cs*16;
  const int cbase=colH0+ch*16, pbase=colP0+ch*8;

  // skewed LDS rows: logical k -> phys k + 2*(k>>7)  (sM: k + 2*(k>>6))
  __shared__ double sP[RPB][520];   // x_t (L0) / h_mem0(t) (L1)
  __shared__ double sH[RPB][520];   // own-layer h(t-1)
  __shared__ double sB[RPB][520];   // rh / hc
  __shared__ double sM[RPB][264];   // mem_out
  __shared__ double su[RPB][32];    // update gate (own cols)
  __shared__ double sm[RPB][16];    // memory state (own pcols)

  if (tid<64) sm[tid>>4][tid&15]=0.0;

  auto fs=[](int k){ return k + ((k>>7)<<1); };

  const double* WRU = g_WRUd + (long)lay*1024*1024;
  const float*  WN  = g_WnT  + (long)lay*1024*512;
  const float*  WMGp= g_WMG  + (long)lay*512*1024;
  const double* WMR = g_WmrTd+ (long)lay*512*256;
  const double* WMH = g_WmhTd+ (long)lay*256*512;
  const float* br_ = p.br + lay*HH; const float* bu_ = p.bu + lay*HH;
  const float* bn_ = p.bn + lay*HH; const float* bmh_= p.bmh+ lay*HH;
  const float* bmr_= p.bmr+ lay*PP; const float* bmw_= p.bmw+ lay*PP;
  const float* bmu_= p.bmu+ lay*PP; const float* bd_ = p.bd + lay*PP;
  const float* bs_ = p.bs + lay*PP;
  const double dopa = (double)p.dop[0];
  const double sero = (double)p.ser[0];

  double* rhG = g_rh + (long)lay*BB*HH + (long)r0g*HH;
  double* hcG = g_hc + (long)lay*BB*HH + (long)r0g*HH;
  double* moG = g_mo + (long)lay*BB*PP + (long)r0g*PP;

  const int gidx = rb*2 + lay;
  auto bar=[&](int s){
    __syncthreads();
    if (tid==0){
      unsigned* cnt=&g_sync[(gidx*4+s)*32];
      unsigned* gen=cnt+16;
      unsigned ge=__hip_atomic_load(gen,__ATOMIC_RELAXED,AGT);
      unsigned old=__hip_atomic_fetch_add(cnt,1u,__ATOMIC_RELEASE,AGT);
      if (old==15u){
        __hip_atomic_store(cnt,0u,__ATOMIC_RELAXED,AGT);
        __hip_atomic_fetch_add(gen,1u,__ATOMIC_RELEASE,AGT);
      } else {
        while(__hip_atomic_load(gen,__ATOMIC_RELAXED,AGT)==ge) __builtin_amdgcn_s_sleep(1);
      }
      asm volatile("" ::: "memory");
    }
    __syncthreads();
  };
  auto wait_ge=[&](int l,int s,unsigned v){
    if (tid==0){
      unsigned* gen=&g_sync[((rb*2+l)*4+s)*32+16];
      while(__hip_atomic_load(gen,__ATOMIC_RELAXED,AGT)<v) __builtin_amdgcn_s_sleep(1);
      asm volatile("" ::: "memory");
    }
    __syncthreads();
  };

  // sc1 staging (coalesced; consecutive lanes -> consecutive doubles)
  auto ld512=[&](double dst[RPB][520], const double* src){
    double v[4];
    #pragma unroll
    for (int j=0;j<4;++j){
      int idx=j*512+tid;
      v[j]=__hip_atomic_load(src + (long)(idx>>9)*HH + (idx&511), __ATOMIC_RELAXED, AGT);
    }
    #pragma unroll
    for (int j=0;j<4;++j){
      int idx=j*512+tid; int c=idx&511;
      dst[idx>>9][c + ((c>>7)<<1)] = v[j];
    }
  };
  auto ld256=[&](const double* src){
    double v[2];
    #pragma unroll
    for (int j=0;j<2;++j){
      int idx=j*512+tid;
      v[j]=__hip_atomic_load(src + (long)(idx>>8)*PP + (idx&255), __ATOMIC_RELAXED, AGT);
    }
    #pragma unroll
    for (int j=0;j<2;++j){
      int idx=j*512+tid; int c=idx&255;
      sM[idx>>8][c + ((c>>6)<<1)] = v[j];
    }
  };
  auto ldX=[&](int t){
    float v[4];
    #pragma unroll
    for (int j=0;j<4;++j){
      int idx=j*512+tid;
      v[j]=p.x[((long)(r0g+(idx>>9))*TT + t)*II + (idx&511)];
    }
    #pragma unroll
    for (int j=0;j<4;++j){
      int idx=j*512+tid; int c=idx&511;
      sP[idx>>9][c + ((c>>7)<<1)] = (double)v[j];
    }
  };

  // ---- stages: wave=(row,colhalf); lane=(c,ks); A broadcast from skewed LDS ----
  auto ruS=[&](){
    const int c=lane&15, ks=lane>>4;
    const int col=cbase+c;
    const double* w = WRU + (long)(ks*256)*1024 + col*2;
    const double* a = (ks<2)? &sP[row][260*ks] : &sH[row][260*(ks-2)];
    double racc=0,uacc=0;
    #pragma unroll 2
    for (int h=0;h<2;++h){
      const double* ah = a + h*130;
      const double* wh = w + (long)h*128*1024;
      #pragma unroll 8
      for (int k=0;k<128;++k){
        double av=ah[k];
        double2 wv=*(const double2*)(wh + (long)k*1024);
        racc=fma(av,wv.x,racc); uacc=fma(av,wv.y,uacc);
      }
    }
    racc+=__shfl_xor(racc,16); racc+=__shfl_xor(racc,32);
    uacc+=__shfl_xor(uacc,16); uacc+=__shfl_xor(uacc,32);
    if (lane<16){
      double r=sigd(racc+(double)br_[col]);
      double u=sigd(uacc+(double)bu_[col]);
      su[row][ch*16+c]=u;
      __hip_atomic_store(&rhG[(long)row*HH+col], r*sH[row][fs(col)], __ATOMIC_RELAXED, AGT);
    }
  };
  auto nS=[&](){
    const int c=lane&15, ks=lane>>4;
    const int col=cbase+c;
    const float* w = WN + (long)(ks*256)*512 + col;
    const double* a = (ks<2)? &sP[row][260*ks] : &sB[row][260*(ks-2)];
    double acc=0,acc2=0;
    #pragma unroll 2
    for (int h=0;h<2;++h){
      const double* ah=a+h*130;
      const float* wh=w+(long)h*128*512;
      #pragma unroll 8
      for (int k=0;k<128;k+=2){
        acc =fma(ah[k],  (double)wh[(long)k*512],    acc);
        acc2=fma(ah[k+1],(double)wh[(long)(k+1)*512],acc2);
      }
    }
    double o=acc+acc2;
    o+=__shfl_xor(o,16); o+=__shfl_xor(o,32);
    if (lane<16){
      double nh=tanh(o+(double)bn_[col]);
      double u=su[row][ch*16+c];
      __hip_atomic_store(&hcG[(long)row*HH+col],
        (1.0-u)*sH[row][fs(col)]+u*nh, __ATOMIC_RELAXED, AGT);
    }
  };
  auto mgS=[&](){
    const int pc=lane&7, ks=lane>>3;
    const int pcol=pbase+pc;
    const float* w4 = WMGp + (long)(ks*64)*1024 + pcol*4;
    const double* a = &sH[row][ks*64 + ((ks>>1)<<1)];
    double q0=0,q1=0,q2=0,q3=0;
    #pragma unroll 8
    for (int k=0;k<64;++k){
      double av=a[k];
      float4 v=*(const float4*)(w4 + (long)k*1024);
      q0=fma(av,(double)v.x,q0); q1=fma(av,(double)v.y,q1);
      q2=fma(av,(double)v.z,q2); q3=fma(av,(double)v.w,q3);
    }
    q0+=__shfl_xor(q0,8); q0+=__shfl_xor(q0,16); q0+=__shfl_xor(q0,32);
    q1+=__shfl_xor(q1,8); q1+=__shfl_xor(q1,16); q1+=__shfl_xor(q1,32);
    q2+=__shfl_xor(q2,8); q2+=__shfl_xor(q2,16); q2+=__shfl_xor(q2,32);
    q3+=__shfl_xor(q3,8); q3+=__shfl_xor(q3,16); q3+=__shfl_xor(q3,32);
    if (lane<8){
      double wg=sigd(q0+(double)bmw_[pcol]);
      double nm=tanh(q1+(double)bmu_[pcol]);
      double dp=sigd((q2+(double)bd_[pcol])*dopa);
      double sr=sigd((q3+(double)bs_[pcol])*sero);
      double ww=wg*dp*(1.0-sr);
      sm[row][ch*8+pc]=(1.0-ww)*sm[row][ch*8+pc]+ww*nm;
    }
  };
  auto rgS=[&](){
    const int pc=lane&7, ks=lane>>3;
    const int pcol=pbase+pc;
    const double* w = WMR + (long)(ks*64)*256 + pcol;
    const double* a = &sB[row][ks*64 + ((ks>>1)<<1)];
    double o=0,o2=0;
    #pragma unroll 8
    for (int k=0;k<64;k+=2){
      o =fma(a[k],  w[(long)k*256],    o);
      o2=fma(a[k+1],w[(long)(k+1)*256],o2);
    }
    o+=o2; o+=__shfl_xor(o,8); o+=__shfl_xor(o,16); o+=__shfl_xor(o,32);
    if (lane<8){
      __hip_atomic_store(&moG[(long)row*PP+pcol],
        sigd(o+(double)bmr_[pcol])*sm[row][ch*8+pc], __ATOMIC_RELAXED, AGT);
    }
  };
  auto hmS=[&](int t){
    const int c=lane&15, ks=lane>>4;
    const int col=cbase+c;
    const double* w = WMH + (long)(ks*64)*512 + col;
    const double* a = &sM[row][66*ks];
    double o=0,o2=0;
    #pragma unroll 8
    for (int k=0;k<64;k+=2){
      o =fma(a[k],  w[(long)k*512],    o);
      o2=fma(a[k+1],w[(long)(k+1)*512],o2);
    }
    o+=o2; o+=__shfl_xor(o,16); o+=__shfl_xor(o,32);
    if (lane<16){
      double hv = o + (double)bmh_[col] + sB[row][fs(col)];
      long gi=(long)(r0g+row)*HH+col;
      if (lay==0){
        __hip_atomic_store(&g_h0d[(long)(t&1)*BB*HH+gi],hv,__ATOMIC_RELAXED,AGT);
      } else {
        __hip_atomic_store(&g_h1[gi],hv,__ATOMIC_RELAXED,AGT);
        __builtin_nontemporal_store(hv,&g_hist[((long)(r0g+row)*TT+t)*HH+col]);
      }
    }
  };

  for (int t=0; t<TT; ++t){
    // St1: ru (+ deferred mg(t-1) on sH = h(t-1))
    if (lay==0){
      ldX(t);
      ld512(sH, &g_h0d[(long)((t+1)&1)*BB*HH + (long)r0g*HH]);
    } else {
      wait_ge(0,3,(unsigned)(t+1));                 // h_mem0(t) ready
      ld512(sP, &g_h0d[(long)(t&1)*BB*HH + (long)r0g*HH]);
      ld512(sH, g_h1 + (long)r0g*HH);
    }
    __syncthreads();
    ruS();
    if (t>0) mgS();
    bar(0);
    // St2: n -> h_cand
    ld512(sB, rhG);
    __syncthreads();
    nS();
    bar(1);
    // St3: read gate -> mem_out
    ld512(sB, hcG);
    __syncthreads();
    rgS();
    bar(2);
    // St4: h_mem (sB = hc kept)
    ld256(moG);
    __syncthreads();
    if (lay==0 && t>=2) wait_ge(1,0,(unsigned)(t-1)); // back-pressure on h0 buffer
    hmS(t);
    bar(3);
  }

  // deferred mg flush for t = TT-1
  if (lay==0) ld512(sH, &g_h0d[(long)((TT-1)&1)*BB*HH + (long)r0g*HH]);
  else        ld512(sH, g_h1 + (long)r0g*HH);
  __syncthreads();
  mgS();
  __syncthreads();

  // finals appended after outputs, FP32: h_final [2,B,H], m_final [2,B,P]
  const long ob=(long)BB*TT*OO;
  if (tid<128){
    int r=tid>>5, c=tid&31; int col=colH0+c; long bq=r0g+r;
    p.out[ob + (long)lay*BB*HH + bq*HH + col] = (float)sH[r][fs(col)];
  }
  if (tid<64){
    int r=tid>>4, pc=tid&15; int pcol=colP0+pc; long bq=r0g+r;
    p.out[ob + 2L*BB*HH + (long)lay*BB*PP + bq*PP + pcol] = (float)sm[r][pc];
  }
}

// outputs[b,t,:] = Wout @ h_mem1[b,t,:] + bout — LDS-staged hist rows, f64 WoutT
__global__ void __launch_bounds__(512) out_gemm(const float* bout, float* out)
{
  __shared__ double sH[8][512];
  const int tid = threadIdx.x;
  const int iw = tid >> 6, lane = tid & 63;
  const int kq = lane >> 5, c32 = lane & 31;
  const int col = iw*64 + c32*2;
  const double* w = g_WoutTd + kq*(256*512) + col;
  for (int rbx = blockIdx.x; rbx < BB*TT/8; rbx += gridDim.x){
    __syncthreads();
    for (int i = tid; i < 8*256; i += 512){
      int rr = i >> 8, c2 = (i & 255) << 1;
      *(double2*)&sH[rr][c2] = *(const double2*)(g_hist + (long)(rbx*8+rr)*HH + c2);
    }
    __syncthreads();
    double s[8][2];
    #pragma unroll
    for (int r=0;r<8;++r){ s[r][0]=0.0; s[r][1]=0.0; }
    #pragma unroll 2
    for (int k=0;k<256;++k){
      double2 wv = *(const double2*)(w + (long)k*512);
      #pragma unroll
      for (int r=0;r<8;++r){
        double av = sH[r][kq*256 + k];
        s[r][0] = fma(av, wv.x, s[r][0]);
        s[r][1] = fma(av, wv.y, s[r][1]);
      }
    }
    #pragma unroll
    for (int r=0;r<8;++r){
      double t0 = s[r][0] + __shfl_xor(s[r][0],32);
      double t1 = s[r][1] + __shfl_xor(s[r][1],32);
      if (lane < 32){
        float2 fv;
        fv.x = (float)(t0 + (double)bout[col]);
        fv.y = (float)(t1 + (double)bout[col+1]);
        *(float2*)&out[(long)(rbx*8+r)*OO + col] = fv;
      }
    }
  }
}

extern "C" void kernel_launch(void* const* d_in, const int* in_sizes, int n_in,
                              void* d_out, int out_size, void* d_ws, size_t ws_size,
                              hipStream_t stream)
{
  KP p;
  p.x   = (const float*)d_in[0];
  p.Wr  = (const float*)d_in[1];  p.br  = (const float*)d_in[2];
  p.Wu  = (const float*)d_in[3];  p.bu  = (const float*)d_in[4];
  p.Wn  = (const float*)d_in[5];  p.bn  = (const float*)d_in[6];
  p.Wmr = (const float*)d_in[7];  p.bmr = (const float*)d_in[8];
  p.Wmw = (const float*)d_in[9];  p.bmw = (const float*)d_in[10];
  p.Wmu = (const float*)d_in[11]; p.bmu = (const float*)d_in[12];
  p.Wmh = (const float*)d_in[13]; p.bmh = (const float*)d_in[14];
  p.Wd  = (const float*)d_in[15]; p.bd  = (const float*)d_in[16];
  p.Ws  = (const float*)d_in[17]; p.bs  = (const float*)d_in[18];
  p.Wout= (const float*)d_in[19]; p.bout= (const float*)d_in[20];
  p.dop = (const float*)d_in[21]; p.ser = (const float*)d_in[22];
  p.out = (float*)d_out;

  prep<<<dim3(5120), dim3(256), 0, stream>>>(p);
  rnn_kernel<<<dim3(NBLK), dim3(NTHR), 0, stream>>>(p);
  out_gemm<<<dim3(2048), dim3(512), 0, stream>>>(p.bout, p.out);
}

// Round 6
// 69749.768 us; speedup vs baseline: 1.6481x; 1.6481x over previous
//
#include <hip/hip_runtime.h>
#include <math.h>

#define BB 64
#define TT 512
#define II 512
#define HH 512
#define PP 256
#define OO 512

#define NBLK 512
#define NTHR 512
#define RPB 4
#define AGT __HIP_MEMORY_SCOPE_AGENT

// ---- mutable fp64 state; all cross-block accesses via agent-scope (sc1) relaxed atomics ----
__device__ __align__(256) double g_h0d[2*BB*HH];   // double-buffered h_mem0 (by t&1)
__device__ __align__(256) double g_h1 [BB*HH];
__device__ __align__(256) double g_rh [2*BB*HH];   // per-layer
__device__ __align__(256) double g_hc [2*BB*HH];
__device__ __align__(256) double g_mo [2*BB*PP];
__device__ __align__(256) double g_hist[(long)BB*TT*HH];
__device__ unsigned g_sync[4096];                  // 32 groups x 4 stages, 128B apart

// ---- transposed weights, ALL f32 (per-XCD slice 2.25 MB -> L2-resident) ----
__device__ __align__(256) float g_WRU [2*1024*1024];  // [l][k][c*2+{r,u}]
__device__ __align__(256) float g_WnT2[2*512*1024];   // [l][k>>1][c*2+(k&1)]  (k-pair interleave)
__device__ __align__(256) float g_WMG [2*512*1024];   // [l][k][pc*4+{mw,mu,d,s}]
__device__ __align__(256) float g_WmrT[2*512*256];    // [l][k][pc]
__device__ __align__(256) float g_WmhT[2*256*512];    // [l][k][c]
__device__ __align__(256) float g_WoutT[512*512];     // [k][c]

struct KP {
  const float *x,*Wr,*br,*Wu,*bu,*Wn,*bn,*Wmr,*bmr,*Wmw,*bmw,*Wmu,*bmu,
              *Wmh,*bmh,*Wd,*bd,*Ws,*bs,*Wout,*bout,*dop,*ser;
  float* out;
};

__device__ inline double sigd(double x){ return 1.0/(1.0+exp(-x)); }

// ---- prep: LDS-tiled transposes (both sides coalesced) + state/sync zeroing ----
__global__ void __launch_bounds__(256) prep(KP p)
{
  __shared__ float tile[32][33];
  const int b = blockIdx.x;
  const int T_RUN = 3072;          // Wr,Wu,Wn
  const int T_MG  = T_RUN + 1024;  // Wmw,Wmu,Wd,Ws
  const int T_MR  = T_MG  + 256;
  const int T_MH  = T_MR  + 256;
  const int T_OUT = T_MH  + 256;
  const int tid = threadIdx.x;

  const float* src=nullptr; float* dst=nullptr;
  int K=0,C=0,st=1,off=0,k0=0,c0=0,mode=0;
  bool xpose=true;

  if (b < T_RUN){
    int m=b>>10, r=b&1023, l=r>>9, t=r&511;
    K=1024; C=512; int ct=t&15, kt=t>>4; k0=kt*32; c0=ct*32;
    src = (m==0? p.Wr : m==1? p.Wu : p.Wn) + (long)l*C*K;
    if (m<2){ dst = g_WRU + (long)l*1024*1024; st=2; off=m; }
    else    { dst = g_WnT2 + (long)l*512*1024; mode=1; }
  } else if (b < T_MG){
    int q=b-T_RUN, m=q>>8, r=q&255, l=r>>7, t=r&127;
    K=512; C=256; int ct=t&7, kt=t>>3; k0=kt*32; c0=ct*32;
    const float* s4[4]={p.Wmw,p.Wmu,p.Wd,p.Ws};
    src = s4[m] + (long)l*C*K;
    dst = g_WMG + (long)l*512*1024; st=4; off=m;
  } else if (b < T_MR){
    int r=b-T_MG, l=r>>7, t=r&127;
    K=512; C=256; int ct=t&7, kt=t>>3; k0=kt*32; c0=ct*32;
    src = p.Wmr + (long)l*C*K;
    dst = g_WmrT + (long)l*512*256; st=1; off=0;
  } else if (b < T_MH){
    int r=b-T_MR, l=r>>7, t=r&127;
    K=256; C=512; int ct=t&15, kt=t>>4; k0=kt*32; c0=ct*32;
    src = p.Wmh + (long)l*C*K;
    dst = g_WmhT + (long)l*256*512; st=1; off=0;
  } else if (b < T_OUT){
    int t=b-T_MH;
    K=512; C=512; int ct=t&15, kt=t>>4; k0=kt*32; c0=ct*32;
    src = p.Wout; dst = g_WoutT; st=1; off=0;
  } else {
    xpose=false;
    long i = (long)(b-T_OUT)*256 + tid;
    if (i < 2L*BB*HH) g_h0d[i]=0.0;
    if (i < (long)BB*HH) g_h1[i]=0.0;
    if (i < 4096) g_sync[(int)i]=0u;
  }

  if (xpose){
    for (int i=tid;i<1024;i+=256){
      int ty=i>>5, tx=i&31;
      tile[ty][tx] = src[(long)(c0+ty)*K + k0+tx];
    }
    __syncthreads();
    for (int i=tid;i<1024;i+=256){
      int ky=i>>5, cx=i&31;
      int k=k0+ky, c=c0+cx;
      long o = mode ? ((long)(k>>1)*1024 + (long)c*2 + (k&1))
                    : ((long)k*C*st + (long)c*st + off);
      dst[o] = tile[cx][ky];
    }
  }
}

// ---- main: 2-layer pipeline, 4-row blocks (2/CU), row-blocked dots (4 rows/wave) ----
__global__ void __launch_bounds__(NTHR,4) rnn_kernel(KP p)
{
  const int tid=threadIdx.x;
  const int xcd=blockIdx.x&7, lay=xcd>>2, xl=xcd&3;
  const int cs=(blockIdx.x>>3)&3, rb=blockIdx.x>>5;   // rb 0..15
  const int iw=tid>>6, lane=tid&63;
  const int r0g=rb*RPB;
  const int colH0=xl*128+cs*32, colP0=xl*64+cs*16;
  const int cW = colH0 + iw*4;       // 4 hidden cols per wave
  const int pW = colP0 + iw*2;       // 2 mem cols per wave

  // skew: logical k -> phys k + 2*(k>>6); 64-chunk starts land on 8 distinct banks
  __shared__ double sP[RPB][528];   // x_t (L0) / h_mem0(t) (L1)
  __shared__ double sH[RPB][528];   // own-layer h(t-1)
  __shared__ double sB[RPB][528];   // rh / hc
  __shared__ double sM[RPB][264];   // mem_out
  __shared__ double su[RPB][32];    // update gate (own cols)
  __shared__ double sm[RPB][16];    // memory state (own pcols)

  if (tid<64) sm[tid>>4][tid&15]=0.0;

  auto fs=[](int k){ return k + ((k>>6)<<1); };

  const float* WRU = g_WRU  + (long)lay*1024*1024;
  const float* WN2 = g_WnT2 + (long)lay*512*1024;
  const float* WMGp= g_WMG  + (long)lay*512*1024;
  const float* WMR = g_WmrT + (long)lay*512*256;
  const float* WMH = g_WmhT + (long)lay*256*512;
  const float* br_ = p.br + lay*HH; const float* bu_ = p.bu + lay*HH;
  const float* bn_ = p.bn + lay*HH; const float* bmh_= p.bmh+ lay*HH;
  const float* bmr_= p.bmr+ lay*PP; const float* bmw_= p.bmw+ lay*PP;
  const float* bmu_= p.bmu+ lay*PP; const float* bd_ = p.bd + lay*PP;
  const float* bs_ = p.bs + lay*PP;
  const double dopa = (double)p.dop[0];
  const double sero = (double)p.ser[0];

  double* rhG = g_rh + (long)lay*BB*HH + (long)r0g*HH;
  double* hcG = g_hc + (long)lay*BB*HH + (long)r0g*HH;
  double* moG = g_mo + (long)lay*BB*PP + (long)r0g*PP;

  const int gidx = rb*2 + lay;
  auto bar=[&](int s){
    __syncthreads();
    if (tid==0){
      unsigned* cnt=&g_sync[(gidx*4+s)*32];
      unsigned* gen=cnt+16;
      unsigned ge=__hip_atomic_load(gen,__ATOMIC_RELAXED,AGT);
      unsigned old=__hip_atomic_fetch_add(cnt,1u,__ATOMIC_RELEASE,AGT);
      if (old==15u){
        __hip_atomic_store(cnt,0u,__ATOMIC_RELAXED,AGT);
        __hip_atomic_fetch_add(gen,1u,__ATOMIC_RELEASE,AGT);
      } else {
        while(__hip_atomic_load(gen,__ATOMIC_RELAXED,AGT)==ge) __builtin_amdgcn_s_sleep(1);
      }
      asm volatile("" ::: "memory");
    }
    __syncthreads();
  };
  auto wait_ge=[&](int l,int s,unsigned v){
    if (tid==0){
      unsigned* gen=&g_sync[((rb*2+l)*4+s)*32+16];
      while(__hip_atomic_load(gen,__ATOMIC_RELAXED,AGT)<v) __builtin_amdgcn_s_sleep(1);
      asm volatile("" ::: "memory");
    }
    __syncthreads();
  };

  // sc1 staging (coalesced; skew applied on LDS write)
  auto ld512=[&](double dst[RPB][528], const double* src){
    double v[4];
    #pragma unroll
    for (int j=0;j<4;++j){
      int idx=j*512+tid;
      v[j]=__hip_atomic_load(src + (long)(idx>>9)*HH + (idx&511), __ATOMIC_RELAXED, AGT);
    }
    #pragma unroll
    for (int j=0;j<4;++j){
      int idx=j*512+tid; int c=idx&511;
      dst[idx>>9][c + ((c>>6)<<1)] = v[j];
    }
  };
  auto ld256=[&](const double* src){
    double v[2];
    #pragma unroll
    for (int j=0;j<2;++j){
      int idx=j*512+tid;
      v[j]=__hip_atomic_load(src + (long)(idx>>8)*PP + (idx&255), __ATOMIC_RELAXED, AGT);
    }
    #pragma unroll
    for (int j=0;j<2;++j){
      int idx=j*512+tid; int c=idx&255;
      sM[idx>>8][c + ((c>>6)<<1)] = v[j];
    }
  };
  auto ldX=[&](int t){
    float v[4];
    #pragma unroll
    for (int j=0;j<4;++j){
      int idx=j*512+tid;
      v[j]=p.x[((long)(r0g+(idx>>9))*TT + t)*II + (idx&511)];
    }
    #pragma unroll
    for (int j=0;j<4;++j){
      int idx=j*512+tid; int c=idx&511;
      sP[idx>>9][c + ((c>>6)<<1)] = (double)v[j];
    }
  };

  // ---- stages: lane=(c|pc, row-tag, ks); 4-row register blocking ----
  auto ruS=[&](){
    const int c=lane&3, ks=lane>>2;                 // ks 0..15, 64-chunks over [A1|Ah]
    const int col=cW+c;
    const float* w = WRU + (long)(ks*64)*1024 + col*2;
    const double* a = (ks<8)? &sP[0][66*ks] : &sH[0][66*(ks-8)];
    double ar[4]={0,0,0,0}, au[4]={0,0,0,0};
    #pragma unroll 4
    for (int k=0;k<64;k+=2){
      float2 w0=*(const float2*)(w + (long)k*1024);
      float2 w1=*(const float2*)(w + (long)(k+1)*1024);
      double wr0=(double)w0.x, wu0=(double)w0.y;
      double wr1=(double)w1.x, wu1=(double)w1.y;
      #pragma unroll
      for (int j=0;j<4;++j){
        double2 av=*(const double2*)(a + j*528 + k);
        ar[j]=fma(av.x,wr0,ar[j]); au[j]=fma(av.x,wu0,au[j]);
        ar[j]=fma(av.y,wr1,ar[j]); au[j]=fma(av.y,wu1,au[j]);
      }
    }
    #pragma unroll
    for (int j=0;j<4;++j){
      ar[j]+=__shfl_xor(ar[j],4);  au[j]+=__shfl_xor(au[j],4);
      ar[j]+=__shfl_xor(ar[j],8);  au[j]+=__shfl_xor(au[j],8);
      ar[j]+=__shfl_xor(ar[j],16); au[j]+=__shfl_xor(au[j],16);
      ar[j]+=__shfl_xor(ar[j],32); au[j]+=__shfl_xor(au[j],32);
    }
    if (lane<4){
      #pragma unroll
      for (int j=0;j<4;++j){
        double r=sigd(ar[j]+(double)br_[col]);
        double u=sigd(au[j]+(double)bu_[col]);
        su[j][iw*4+c]=u;
        __hip_atomic_store(&rhG[(long)j*HH+col], r*sH[j][fs(col)], __ATOMIC_RELAXED, AGT);
      }
    }
  };
  auto nS=[&](){
    const int c=lane&3, ks=lane>>2;
    const int col=cW+c;
    const float* w = WN2 + (long)(ks*32)*1024 + col*2;   // (koff>>1)*1024, koff=ks*64
    const double* a = (ks<8)? &sP[0][66*ks] : &sB[0][66*(ks-8)];
    double ac[4]={0,0,0,0};
    #pragma unroll 4
    for (int kp=0;kp<32;++kp){
      float2 wv=*(const float2*)(w + (long)kp*1024);
      double w0=(double)wv.x, w1=(double)wv.y;
      #pragma unroll
      for (int j=0;j<4;++j){
        double2 av=*(const double2*)(a + j*528 + kp*2);
        ac[j]=fma(av.x,w0,ac[j]); ac[j]=fma(av.y,w1,ac[j]);
      }
    }
    #pragma unroll
    for (int j=0;j<4;++j){
      ac[j]+=__shfl_xor(ac[j],4);  ac[j]+=__shfl_xor(ac[j],8);
      ac[j]+=__shfl_xor(ac[j],16); ac[j]+=__shfl_xor(ac[j],32);
    }
    if (lane<4){
      #pragma unroll
      for (int j=0;j<4;++j){
        double nh=tanh(ac[j]+(double)bn_[col]);
        double u=su[j][iw*4+c];
        __hip_atomic_store(&hcG[(long)j*HH+col],
          (1.0-u)*sH[j][fs(col)]+u*nh, __ATOMIC_RELAXED, AGT);
      }
    }
  };
  auto mgS=[&](){
    const int pc=lane&1, j=(lane>>1)&3, ks=lane>>3;   // ks 0..7, 64-chunks over 512
    const int pcol=pW+pc;
    const float* w4 = WMGp + (long)(ks*64)*1024 + pcol*4;
    const double* a = &sH[j][66*ks];
    double q0=0,q1=0,q2=0,q3=0;
    #pragma unroll 4
    for (int k=0;k<64;++k){
      double av=a[k];
      float4 v=*(const float4*)(w4 + (long)k*1024);
      q0=fma(av,(double)v.x,q0); q1=fma(av,(double)v.y,q1);
      q2=fma(av,(double)v.z,q2); q3=fma(av,(double)v.w,q3);
    }
    q0+=__shfl_xor(q0,8); q0+=__shfl_xor(q0,16); q0+=__shfl_xor(q0,32);
    q1+=__shfl_xor(q1,8); q1+=__shfl_xor(q1,16); q1+=__shfl_xor(q1,32);
    q2+=__shfl_xor(q2,8); q2+=__shfl_xor(q2,16); q2+=__shfl_xor(q2,32);
    q3+=__shfl_xor(q3,8); q3+=__shfl_xor(q3,16); q3+=__shfl_xor(q3,32);
    if (lane<8){
      double wg=sigd(q0+(double)bmw_[pcol]);
      double nm=tanh(q1+(double)bmu_[pcol]);
      double dp=sigd((q2+(double)bd_[pcol])*dopa);
      double sr=sigd((q3+(double)bs_[pcol])*sero);
      double ww=wg*dp*(1.0-sr);
      sm[j][iw*2+pc]=(1.0-ww)*sm[j][iw*2+pc]+ww*nm;
    }
  };
  auto rgS=[&](){
    const int pc=lane&1, j=(lane>>1)&3, ks=lane>>3;
    const int pcol=pW+pc;
    const float* w = WMR + (long)(ks*64)*256 + pcol;
    const double* a = &sB[j][66*ks];
    double o=0,o2=0;
    #pragma unroll 8
    for (int k=0;k<64;k+=2){
      o =fma(a[k],  (double)w[(long)k*256],    o);
      o2=fma(a[k+1],(double)w[(long)(k+1)*256],o2);
    }
    o+=o2; o+=__shfl_xor(o,8); o+=__shfl_xor(o,16); o+=__shfl_xor(o,32);
    if (lane<8){
      __hip_atomic_store(&moG[(long)j*PP+pcol],
        sigd(o+(double)bmr_[pcol])*sm[j][iw*2+pc], __ATOMIC_RELAXED, AGT);
    }
  };
  auto hmS=[&](int t){
    const int c=lane&3, j=(lane>>2)&3, ks=lane>>4;    // ks 0..3, 64-chunks over 256
    const int col=cW+c;
    const float* w = WMH + (long)(ks*64)*512 + col;
    const double* a = &sM[j][66*ks];
    double o=0,o2=0;
    #pragma unroll 8
    for (int k=0;k<64;k+=2){
      o =fma(a[k],  (double)w[(long)k*512],    o);
      o2=fma(a[k+1],(double)w[(long)(k+1)*512],o2);
    }
    o+=o2; o+=__shfl_xor(o,16); o+=__shfl_xor(o,32);
    if (lane<16){
      double hv = o + (double)bmh_[col] + sB[j][fs(col)];
      long gi=(long)(r0g+j)*HH+col;
      if (lay==0){
        __hip_atomic_store(&g_h0d[(long)(t&1)*BB*HH+gi],hv,__ATOMIC_RELAXED,AGT);
      } else {
        __hip_atomic_store(&g_h1[gi],hv,__ATOMIC_RELAXED,AGT);
        __builtin_nontemporal_store(hv,&g_hist[((long)(r0g+j)*TT+t)*HH+col]);
      }
    }
  };

  for (int t=0; t<TT; ++t){
    // St1: ru (+ deferred mg(t-1) on sH = h(t-1))
    if (lay==0){
      ldX(t);
      ld512(sH, &g_h0d[(long)((t+1)&1)*BB*HH + (long)r0g*HH]);
    } else {
      wait_ge(0,3,(unsigned)(t+1));                 // h_mem0(t) ready
      ld512(sP, &g_h0d[(long)(t&1)*BB*HH + (long)r0g*HH]);
      ld512(sH, g_h1 + (long)r0g*HH);
    }
    __syncthreads();
    ruS();
    if (t>0) mgS();
    bar(0);
    // St2: n -> h_cand
    ld512(sB, rhG);
    __syncthreads();
    nS();
    bar(1);
    // St3: read gate -> mem_out
    ld512(sB, hcG);
    __syncthreads();
    rgS();
    bar(2);
    // St4: h_mem (sB = hc kept)
    ld256(moG);
    __syncthreads();
    if (lay==0 && t>=2) wait_ge(1,0,(unsigned)(t-1)); // back-pressure on h0 buffer
    hmS(t);
    bar(3);
  }

  // deferred mg flush for t = TT-1
  if (lay==0) ld512(sH, &g_h0d[(long)((TT-1)&1)*BB*HH + (long)r0g*HH]);
  else        ld512(sH, g_h1 + (long)r0g*HH);
  __syncthreads();
  mgS();
  __syncthreads();

  // finals appended after outputs, FP32: h_final [2,B,H], m_final [2,B,P]
  const long ob=(long)BB*TT*OO;
  if (tid<128){
    int r=tid>>5, c=tid&31; int col=colH0+c; long bq=r0g+r;
    p.out[ob + (long)lay*BB*HH + bq*HH + col] = (float)sH[r][fs(col)];
  }
  if (tid<64){
    int r=tid>>4, pc=tid&15; int pcol=colP0+pc; long bq=r0g+r;
    p.out[ob + 2L*BB*HH + (long)lay*BB*PP + bq*PP + pcol] = (float)sm[r][pc];
  }
}

// outputs[b,t,:] = Wout @ h_mem1[b,t,:] + bout — LDS-staged hist rows, f32 WoutT
__global__ void __launch_bounds__(512) out_gemm(const float* bout, float* out)
{
  __shared__ double sH[8][512];
  const int tid = threadIdx.x;
  const int iw = tid >> 6, lane = tid & 63;
  const int kq = lane >> 5, c32 = lane & 31;
  const int col = iw*64 + c32*2;
  const float* w = g_WoutT + kq*(256*512) + col;
  for (int rbx = blockIdx.x; rbx < BB*TT/8; rbx += gridDim.x){
    __syncthreads();
    for (int i = tid; i < 8*256; i += 512){
      int rr = i >> 8, c2 = (i & 255) << 1;
      *(double2*)&sH[rr][c2] = *(const double2*)(g_hist + (long)(rbx*8+rr)*HH + c2);
    }
    __syncthreads();
    double s[8][2];
    #pragma unroll
    for (int r=0;r<8;++r){ s[r][0]=0.0; s[r][1]=0.0; }
    #pragma unroll 2
    for (int k=0;k<256;++k){
      float2 wv = *(const float2*)(w + (long)k*512);
      double wx = (double)wv.x, wy = (double)wv.y;
      #pragma unroll
      for (int r=0;r<8;++r){
        double av = sH[r][kq*256 + k];
        s[r][0] = fma(av, wx, s[r][0]);
        s[r][1] = fma(av, wy, s[r][1]);
      }
    }
    #pragma unroll
    for (int r=0;r<8;++r){
      double t0 = s[r][0] + __shfl_xor(s[r][0],32);
      double t1 = s[r][1] + __shfl_xor(s[r][1],32);
      if (lane < 32){
        float2 fv;
        fv.x = (float)(t0 + (double)bout[col]);
        fv.y = (float)(t1 + (double)bout[col+1]);
        *(float2*)&out[(long)(rbx*8+r)*OO + col] = fv;
      }
    }
  }
}

extern "C" void kernel_launch(void* const* d_in, const int* in_sizes, int n_in,
                              void* d_out, int out_size, void* d_ws, size_t ws_size,
                              hipStream_t stream)
{
  KP p;
  p.x   = (const float*)d_in[0];
  p.Wr  = (const float*)d_in[1];  p.br  = (const float*)d_in[2];
  p.Wu  = (const float*)d_in[3];  p.bu  = (const float*)d_in[4];
  p.Wn  = (const float*)d_in[5];  p.bn  = (const float*)d_in[6];
  p.Wmr = (const float*)d_in[7];  p.bmr = (const float*)d_in[8];
  p.Wmw = (const float*)d_in[9];  p.bmw = (const float*)d_in[10];
  p.Wmu = (const float*)d_in[11]; p.bmu = (const float*)d_in[12];
  p.Wmh = (const float*)d_in[13]; p.bmh = (const float*)d_in[14];
  p.Wd  = (const float*)d_in[15]; p.bd  = (const float*)d_in[16];
  p.Ws  = (const float*)d_in[17]; p.bs  = (const float*)d_in[18];
  p.Wout= (const float*)d_in[19]; p.bout= (const float*)d_in[20];
  p.dop = (const float*)d_in[21]; p.ser = (const float*)d_in[22];
  p.out = (float*)d_out;

  prep<<<dim3(5120), dim3(256), 0, stream>>>(p);
  rnn_kernel<<<dim3(NBLK), dim3(NTHR), 0, stream>>>(p);
  out_gemm<<<dim3(2048), dim3(512), 0, stream>>>(p.bout, p.out);
}

// Round 7
// 67156.104 us; speedup vs baseline: 1.7118x; 1.0386x over previous
//
#include <hip/hip_runtime.h>
#include <math.h>

#define BB 64
#define TT 512
#define II 512
#define HH 512
#define PP 256
#define OO 512

#define NBLK 256
#define NTHR 1024
#define RPB 8
#define AGT __HIP_MEMORY_SCOPE_AGENT

// ---- mutable fp64 state; all cross-block accesses via agent-scope (sc1) relaxed atomics ----
__device__ __align__(256) double g_h0d[2*BB*HH];   // double-buffered h_mem0 (by t&1)
__device__ __align__(256) double g_h1 [BB*HH];
__device__ __align__(256) double g_rh [2*BB*HH];   // per-layer
__device__ __align__(256) double g_hc [2*BB*HH];
__device__ __align__(256) double g_mo [2*BB*PP];
__device__ __align__(256) double g_hist[(long)BB*TT*HH];
__device__ unsigned g_sync[4096];                  // 16 groups x 4 stages, 128B apart

// ---- transposed weights, ALL f32 (per-XCD slice ~2.3 MB -> L2-resident) ----
__device__ __align__(256) float g_WRU [2*1024*1024];  // [l][k][c*2+{r,u}]
__device__ __align__(256) float g_WnT2[2*512*1024];   // [l][k>>1][c*2+(k&1)]
__device__ __align__(256) float g_WMG [2*512*1024];   // [l][k][pc*4+{mw,mu,d,s}]
__device__ __align__(256) float g_WmrT[2*512*256];    // [l][k][pc]
__device__ __align__(256) float g_WmhT[2*256*512];    // [l][k][c]
__device__ __align__(256) float g_WoutT[512*512];     // [k][c]

struct KP {
  const float *x,*Wr,*br,*Wu,*bu,*Wn,*bn,*Wmr,*bmr,*Wmw,*bmw,*Wmu,*bmu,
              *Wmh,*bmh,*Wd,*bd,*Ws,*bs,*Wout,*bout,*dop,*ser;
  float* out;
};

__device__ inline double sigd(double x){ return 1.0/(1.0+exp(-x)); }

// ---- prep: LDS-tiled transposes (both sides coalesced) + state/sync zeroing ----
__global__ void __launch_bounds__(256) prep(KP p)
{
  __shared__ float tile[32][33];
  const int b = blockIdx.x;
  const int T_RUN = 3072;          // Wr,Wu,Wn
  const int T_MG  = T_RUN + 1024;  // Wmw,Wmu,Wd,Ws
  const int T_MR  = T_MG  + 256;
  const int T_MH  = T_MR  + 256;
  const int T_OUT = T_MH  + 256;
  const int tid = threadIdx.x;

  const float* src=nullptr; float* dst=nullptr;
  int K=0,C=0,st=1,off=0,k0=0,c0=0,mode=0;
  bool xpose=true;

  if (b < T_RUN){
    int m=b>>10, r=b&1023, l=r>>9, t=r&511;
    K=1024; C=512; int ct=t&15, kt=t>>4; k0=kt*32; c0=ct*32;
    src = (m==0? p.Wr : m==1? p.Wu : p.Wn) + (long)l*C*K;
    if (m<2){ dst = g_WRU + (long)l*1024*1024; st=2; off=m; }
    else    { dst = g_WnT2 + (long)l*512*1024; mode=1; }
  } else if (b < T_MG){
    int q=b-T_RUN, m=q>>8, r=q&255, l=r>>7, t=r&127;
    K=512; C=256; int ct=t&7, kt=t>>3; k0=kt*32; c0=ct*32;
    const float* s4[4]={p.Wmw,p.Wmu,p.Wd,p.Ws};
    src = s4[m] + (long)l*C*K;
    dst = g_WMG + (long)l*512*1024; st=4; off=m;
  } else if (b < T_MR){
    int r=b-T_MG, l=r>>7, t=r&127;
    K=512; C=256; int ct=t&7, kt=t>>3; k0=kt*32; c0=ct*32;
    src = p.Wmr + (long)l*C*K;
    dst = g_WmrT + (long)l*512*256; st=1; off=0;
  } else if (b < T_MH){
    int r=b-T_MR, l=r>>7, t=r&127;
    K=256; C=512; int ct=t&15, kt=t>>4; k0=kt*32; c0=ct*32;
    src = p.Wmh + (long)l*C*K;
    dst = g_WmhT + (long)l*256*512; st=1; off=0;
  } else if (b < T_OUT){
    int t=b-T_MH;
    K=512; C=512; int ct=t&15, kt=t>>4; k0=kt*32; c0=ct*32;
    src = p.Wout; dst = g_WoutT; st=1; off=0;
  } else {
    xpose=false;
    long i = (long)(b-T_OUT)*256 + tid;
    if (i < 2L*BB*HH) g_h0d[i]=0.0;
    if (i < (long)BB*HH) g_h1[i]=0.0;
    if (i < 4096) g_sync[(int)i]=0u;
  }

  if (xpose){
    for (int i=tid;i<1024;i+=256){
      int ty=i>>5, tx=i&31;
      tile[ty][tx] = src[(long)(c0+ty)*K + k0+tx];
    }
    __syncthreads();
    for (int i=tid;i<1024;i+=256){
      int ky=i>>5, cx=i&31;
      int k=k0+ky, c=c0+cx;
      long o = mode ? ((long)(k>>1)*1024 + (long)c*2 + (k&1))
                    : ((long)k*C*st + (long)c*st + off);
      dst[o] = tile[cx][ky];
    }
  }
}

// ---- main: 256 blocks (1/CU, proven %8 XCD map), 1024 thr (4 waves/SIMD),
// ---- 8-row blocks, row-blocked dots (4 rows per lane-acc), 2-layer pipeline ----
__global__ void __launch_bounds__(NTHR,4) rnn_kernel(KP p)
{
  const int tid=threadIdx.x;
  const int xcd=blockIdx.x&7, lay=xcd>>2, xl=xcd&3;
  const int cs=(blockIdx.x>>3)&3, rb=blockIdx.x>>5;   // rb 0..7
  const int iw=tid>>6, lane=tid&63;                   // 16 waves
  const int r0g=rb*RPB;
  const int colH0=xl*128+cs*32, colP0=xl*64+cs*16;
  const int cW  = colH0 + (iw>>1)*4;   // ru/n: 4 cols per wave
  const int rset= (iw&1)*4;            // ru/n: 4-row half
  const int cW2 = colH0 + iw*2;        // hm: 2 cols per wave
  const int pW  = colP0 + iw;          // mg/rg: 1 pcol per wave

  // skew: logical k -> phys k + 2*(k>>6)
  __shared__ double sP[RPB][528];   // x_t (L0) / h_mem0(t) (L1)
  __shared__ double sH[RPB][528];   // own-layer h(t-1)
  __shared__ double sB[RPB][528];   // rh / hc
  __shared__ double sM[RPB][265];   // mem_out (row stride 265: rows on distinct banks)
  __shared__ double su[RPB][32];    // update gate (own cols)
  __shared__ double sm[RPB][16];    // memory state (own pcols)

  if (tid<128) sm[tid>>4][tid&15]=0.0;

  auto fs=[](int k){ return k + ((k>>6)<<1); };

  const float* WRU = g_WRU  + (long)lay*1024*1024;
  const float* WN2 = g_WnT2 + (long)lay*512*1024;
  const float* WMGp= g_WMG  + (long)lay*512*1024;
  const float* WMR = g_WmrT + (long)lay*512*256;
  const float* WMH = g_WmhT + (long)lay*256*512;
  const float* br_ = p.br + lay*HH; const float* bu_ = p.bu + lay*HH;
  const float* bn_ = p.bn + lay*HH; const float* bmh_= p.bmh+ lay*HH;
  const float* bmr_= p.bmr+ lay*PP; const float* bmw_= p.bmw+ lay*PP;
  const float* bmu_= p.bmu+ lay*PP; const float* bd_ = p.bd + lay*PP;
  const float* bs_ = p.bs + lay*PP;
  const double dopa = (double)p.dop[0];
  const double sero = (double)p.ser[0];

  double* rhG = g_rh + (long)lay*BB*HH + (long)r0g*HH;
  double* hcG = g_hc + (long)lay*BB*HH + (long)r0g*HH;
  double* moG = g_mo + (long)lay*BB*PP + (long)r0g*PP;

  const int gidx = rb*2 + lay;
  auto bar=[&](int s){
    __syncthreads();
    if (tid==0){
      unsigned* cnt=&g_sync[(gidx*4+s)*32];
      unsigned* gen=cnt+16;
      unsigned ge=__hip_atomic_load(gen,__ATOMIC_RELAXED,AGT);
      unsigned old=__hip_atomic_fetch_add(cnt,1u,__ATOMIC_RELEASE,AGT);
      if (old==15u){
        __hip_atomic_store(cnt,0u,__ATOMIC_RELAXED,AGT);
        __hip_atomic_fetch_add(gen,1u,__ATOMIC_RELEASE,AGT);
      } else {
        while(__hip_atomic_load(gen,__ATOMIC_RELAXED,AGT)==ge) __builtin_amdgcn_s_sleep(1);
      }
      asm volatile("" ::: "memory");
    }
    __syncthreads();
  };
  auto wait_ge=[&](int l,int s,unsigned v){
    if (tid==0){
      unsigned* gen=&g_sync[((rb*2+l)*4+s)*32+16];
      while(__hip_atomic_load(gen,__ATOMIC_RELAXED,AGT)<v) __builtin_amdgcn_s_sleep(1);
      asm volatile("" ::: "memory");
    }
    __syncthreads();
  };

  // sc1 staging (coalesced; skew applied on LDS write)
  auto ld512=[&](double dst[RPB][528], const double* src){
    double v[4];
    #pragma unroll
    for (int j=0;j<4;++j){
      int idx=j*1024+tid;
      v[j]=__hip_atomic_load(src + (long)(idx>>9)*HH + (idx&511), __ATOMIC_RELAXED, AGT);
    }
    #pragma unroll
    for (int j=0;j<4;++j){
      int idx=j*1024+tid; int c=idx&511;
      dst[idx>>9][c + ((c>>6)<<1)] = v[j];
    }
  };
  auto ld256=[&](const double* src){
    double v[2];
    #pragma unroll
    for (int j=0;j<2;++j){
      int idx=j*1024+tid;
      v[j]=__hip_atomic_load(src + (long)(idx>>8)*PP + (idx&255), __ATOMIC_RELAXED, AGT);
    }
    #pragma unroll
    for (int j=0;j<2;++j){
      int idx=j*1024+tid; int c=idx&255;
      sM[idx>>8][c + ((c>>6)<<1)] = v[j];
    }
  };
  auto ldX=[&](int t){
    float v[4];
    #pragma unroll
    for (int j=0;j<4;++j){
      int idx=j*1024+tid;
      v[j]=p.x[((long)(r0g+(idx>>9))*TT + t)*II + (idx&511)];
    }
    #pragma unroll
    for (int j=0;j<4;++j){
      int idx=j*1024+tid; int c=idx&511;
      sP[idx>>9][c + ((c>>6)<<1)] = (double)v[j];
    }
  };

  // ---- stages ----
  // ru: wave=(4 cols cW, 4 rows rset); lane c=lane&3, ks=lane>>2 (16 x 64-chunk over [A1|Ah])
  auto ruS=[&](){
    const int c=lane&3, ks=lane>>2;
    const int col=cW+c;
    const float* w = WRU + (long)(ks*64)*1024 + col*2;
    const double* a = (ks<8)? &sP[rset][66*ks] : &sH[rset][66*(ks-8)];
    double ar[4]={0,0,0,0}, au[4]={0,0,0,0};
    #pragma unroll 4
    for (int k=0;k<64;k+=2){
      float2 w0=*(const float2*)(w + (long)k*1024);
      float2 w1=*(const float2*)(w + (long)(k+1)*1024);
      double wr0=(double)w0.x, wu0=(double)w0.y;
      double wr1=(double)w1.x, wu1=(double)w1.y;
      #pragma unroll
      for (int j=0;j<4;++j){
        double2 av=*(const double2*)(a + j*528 + k);
        ar[j]=fma(av.x,wr0,ar[j]); au[j]=fma(av.x,wu0,au[j]);
        ar[j]=fma(av.y,wr1,ar[j]); au[j]=fma(av.y,wu1,au[j]);
      }
    }
    #pragma unroll
    for (int j=0;j<4;++j){
      ar[j]+=__shfl_xor(ar[j],4);  au[j]+=__shfl_xor(au[j],4);
      ar[j]+=__shfl_xor(ar[j],8);  au[j]+=__shfl_xor(au[j],8);
      ar[j]+=__shfl_xor(ar[j],16); au[j]+=__shfl_xor(au[j],16);
      ar[j]+=__shfl_xor(ar[j],32); au[j]+=__shfl_xor(au[j],32);
    }
    if (lane<4){
      const int colw=cW+lane;
      #pragma unroll
      for (int j=0;j<4;++j){
        double r=sigd(ar[j]+(double)br_[colw]);
        double u=sigd(au[j]+(double)bu_[colw]);
        su[rset+j][(iw>>1)*4+lane]=u;
        __hip_atomic_store(&rhG[(long)(rset+j)*HH+colw], r*sH[rset+j][fs(colw)], __ATOMIC_RELAXED, AGT);
      }
    }
  };
  // n: same geometry; A = [sP | sB(rh)]; WN2 k-pair interleave
  auto nS=[&](){
    const int c=lane&3, ks=lane>>2;
    const int col=cW+c;
    const float* w = WN2 + (long)(ks*32)*1024 + col*2;
    const double* a = (ks<8)? &sP[rset][66*ks] : &sB[rset][66*(ks-8)];
    double ac[4]={0,0,0,0};
    #pragma unroll 4
    for (int kp=0;kp<32;++kp){
      float2 wv=*(const float2*)(w + (long)kp*1024);
      double w0=(double)wv.x, w1=(double)wv.y;
      #pragma unroll
      for (int j=0;j<4;++j){
        double2 av=*(const double2*)(a + j*528 + kp*2);
        ac[j]=fma(av.x,w0,ac[j]); ac[j]=fma(av.y,w1,ac[j]);
      }
    }
    #pragma unroll
    for (int j=0;j<4;++j){
      ac[j]+=__shfl_xor(ac[j],4);  ac[j]+=__shfl_xor(ac[j],8);
      ac[j]+=__shfl_xor(ac[j],16); ac[j]+=__shfl_xor(ac[j],32);
    }
    if (lane<4){
      const int colw=cW+lane;
      #pragma unroll
      for (int j=0;j<4;++j){
        double nh=tanh(ac[j]+(double)bn_[colw]);
        double u=su[rset+j][(iw>>1)*4+lane];
        __hip_atomic_store(&hcG[(long)(rset+j)*HH+colw],
          (1.0-u)*sH[rset+j][fs(colw)]+u*nh, __ATOMIC_RELAXED, AGT);
      }
    }
  };
  // mg: wave = 1 pcol x 8 rows; lane j=lane&7, ks=lane>>3 (8 x 64-chunk over 512)
  auto mgS=[&](){
    const int j=lane&7, ks=lane>>3;
    const float* w4 = WMGp + (long)(ks*64)*1024 + pW*4;
    const double* a = &sH[j][66*ks];
    double q0=0,q1=0,q2=0,q3=0;
    #pragma unroll 4
    for (int k=0;k<64;++k){
      double av=a[k];
      float4 v=*(const float4*)(w4 + (long)k*1024);
      q0=fma(av,(double)v.x,q0); q1=fma(av,(double)v.y,q1);
      q2=fma(av,(double)v.z,q2); q3=fma(av,(double)v.w,q3);
    }
    q0+=__shfl_xor(q0,8); q0+=__shfl_xor(q0,16); q0+=__shfl_xor(q0,32);
    q1+=__shfl_xor(q1,8); q1+=__shfl_xor(q1,16); q1+=__shfl_xor(q1,32);
    q2+=__shfl_xor(q2,8); q2+=__shfl_xor(q2,16); q2+=__shfl_xor(q2,32);
    q3+=__shfl_xor(q3,8); q3+=__shfl_xor(q3,16); q3+=__shfl_xor(q3,32);
    if (lane<8){
      double wg=sigd(q0+(double)bmw_[pW]);
      double nm=tanh(q1+(double)bmu_[pW]);
      double dp=sigd((q2+(double)bd_[pW])*dopa);
      double sr=sigd((q3+(double)bs_[pW])*sero);
      double ww=wg*dp*(1.0-sr);
      sm[lane][iw]=(1.0-ww)*sm[lane][iw]+ww*nm;
    }
  };
  // rg: wave = 1 pcol x 8 rows; A = sB(hc)
  auto rgS=[&](){
    const int j=lane&7, ks=lane>>3;
    const float* w = WMR + (long)(ks*64)*256 + pW;
    const double* a = &sB[j][66*ks];
    double o=0,o2=0;
    #pragma unroll 8
    for (int k=0;k<64;k+=2){
      o =fma(a[k],  (double)w[(long)k*256],    o);
      o2=fma(a[k+1],(double)w[(long)(k+1)*256],o2);
    }
    o+=o2; o+=__shfl_xor(o,8); o+=__shfl_xor(o,16); o+=__shfl_xor(o,32);
    if (lane<8){
      __hip_atomic_store(&moG[(long)lane*PP+pW],
        sigd(o+(double)bmr_[pW])*sm[lane][iw], __ATOMIC_RELAXED, AGT);
    }
  };
  // hm: wave = 2 cols x 8 rows; lane c=lane&1, j=(lane>>1)&7, ks=lane>>4 (4 x 64 over 256)
  auto hmS=[&](int t){
    const int c=lane&1, j=(lane>>1)&7, ks=lane>>4;
    const int col=cW2+c;
    const float* w = WMH + (long)(ks*64)*512 + col;
    const double* a = &sM[j][66*ks];
    double o=0,o2=0;
    #pragma unroll 8
    for (int k=0;k<64;k+=2){
      o =fma(a[k],  (double)w[(long)k*512],    o);
      o2=fma(a[k+1],(double)w[(long)(k+1)*512],o2);
    }
    o+=o2; o+=__shfl_xor(o,16); o+=__shfl_xor(o,32);
    if (lane<16){
      double hv = o + (double)bmh_[col] + sB[j][fs(col)];
      long gi=(long)(r0g+j)*HH+col;
      if (lay==0){
        __hip_atomic_store(&g_h0d[(long)(t&1)*BB*HH+gi],hv,__ATOMIC_RELAXED,AGT);
      } else {
        __hip_atomic_store(&g_h1[gi],hv,__ATOMIC_RELAXED,AGT);
        __builtin_nontemporal_store(hv,&g_hist[((long)(r0g+j)*TT+t)*HH+col]);
      }
    }
  };

  for (int t=0; t<TT; ++t){
    // St1: ru (+ deferred mg(t-1) on sH = h(t-1))
    if (lay==0){
      ldX(t);
      ld512(sH, &g_h0d[(long)((t+1)&1)*BB*HH + (long)r0g*HH]);
    } else {
      wait_ge(0,3,(unsigned)(t+1));                 // h_mem0(t) ready
      ld512(sP, &g_h0d[(long)(t&1)*BB*HH + (long)r0g*HH]);
      ld512(sH, g_h1 + (long)r0g*HH);
    }
    __syncthreads();
    ruS();
    if (t>0) mgS();
    bar(0);
    // St2: n -> h_cand
    ld512(sB, rhG);
    __syncthreads();
    nS();
    bar(1);
    // St3: read gate -> mem_out
    ld512(sB, hcG);
    __syncthreads();
    rgS();
    bar(2);
    // St4: h_mem (sB = hc kept)
    ld256(moG);
    __syncthreads();
    if (lay==0 && t>=2) wait_ge(1,0,(unsigned)(t-1)); // back-pressure on h0 buffer
    hmS(t);
    bar(3);
  }

  // deferred mg flush for t = TT-1
  if (lay==0) ld512(sH, &g_h0d[(long)((TT-1)&1)*BB*HH + (long)r0g*HH]);
  else        ld512(sH, g_h1 + (long)r0g*HH);
  __syncthreads();
  mgS();
  __syncthreads();

  // finals appended after outputs, FP32: h_final [2,B,H], m_final [2,B,P]
  const long ob=(long)BB*TT*OO;
  if (tid<256){
    int r=tid>>5, c=tid&31; int col=colH0+c; long bq=r0g+r;
    p.out[ob + (long)lay*BB*HH + bq*HH + col] = (float)sH[r][fs(col)];
  }
  if (tid<128){
    int r=tid>>4, pc=tid&15; int pcol=colP0+pc; long bq=r0g+r;
    p.out[ob + 2L*BB*HH + (long)lay*BB*PP + bq*PP + pcol] = (float)sm[r][pc];
  }
}

// outputs[b,t,:] = Wout @ h_mem1[b,t,:] + bout — LDS-staged hist rows, f32 WoutT
__global__ void __launch_bounds__(512) out_gemm(const float* bout, float* out)
{
  __shared__ double sH[8][512];
  const int tid = threadIdx.x;
  const int iw = tid >> 6, lane = tid & 63;
  const int kq = lane >> 5, c32 = lane & 31;
  const int col = iw*64 + c32*2;
  const float* w = g_WoutT + kq*(256*512) + col;
  for (int rbx = blockIdx.x; rbx < BB*TT/8; rbx += gridDim.x){
    __syncthreads();
    for (int i = tid; i < 8*256; i += 512){
      int rr = i >> 8, c2 = (i & 255) << 1;
      *(double2*)&sH[rr][c2] = *(const double2*)(g_hist + (long)(rbx*8+rr)*HH + c2);
    }
    __syncthreads();
    double s[8][2];
    #pragma unroll
    for (int r=0;r<8;++r){ s[r][0]=0.0; s[r][1]=0.0; }
    #pragma unroll 2
    for (int k=0;k<256;++k){
      float2 wv = *(const float2*)(w + (long)k*512);
      double wx = (double)wv.x, wy = (double)wv.y;
      #pragma unroll
      for (int r=0;r<8;++r){
        double av = sH[r][kq*256 + k];
        s[r][0] = fma(av, wx, s[r][0]);
        s[r][1] = fma(av, wy, s[r][1]);
      }
    }
    #pragma unroll
    for (int r=0;r<8;++r){
      double t0 = s[r][0] + __shfl_xor(s[r][0],32);
      double t1 = s[r][1] + __shfl_xor(s[r][1],32);
      if (lane < 32){
        float2 fv;
        fv.x = (float)(t0 + (double)bout[col]);
        fv.y = (float)(t1 + (double)bout[col+1]);
        *(float2*)&out[(long)(rbx*8+r)*OO + col] = fv;
      }
    }
  }
}

extern "C" void kernel_launch(void* const* d_in, const int* in_sizes, int n_in,
                              void* d_out, int out_size, void* d_ws, size_t ws_size,
                              hipStream_t stream)
{
  KP p;
  p.x   = (const float*)d_in[0];
  p.Wr  = (const float*)d_in[1];  p.br  = (const float*)d_in[2];
  p.Wu  = (const float*)d_in[3];  p.bu  = (const float*)d_in[4];
  p.Wn  = (const float*)d_in[5];  p.bn  = (const float*)d_in[6];
  p.Wmr = (const float*)d_in[7];  p.bmr = (const float*)d_in[8];
  p.Wmw = (const float*)d_in[9];  p.bmw = (const float*)d_in[10];
  p.Wmu = (const float*)d_in[11]; p.bmu = (const float*)d_in[12];
  p.Wmh = (const float*)d_in[13]; p.bmh = (const float*)d_in[14];
  p.Wd  = (const float*)d_in[15]; p.bd  = (const float*)d_in[16];
  p.Ws  = (const float*)d_in[17]; p.bs  = (const float*)d_in[18];
  p.Wout= (const float*)d_in[19]; p.bout= (const float*)d_in[20];
  p.dop = (const float*)d_in[21]; p.ser = (const float*)d_in[22];
  p.out = (float*)d_out;

  prep<<<dim3(5120), dim3(256), 0, stream>>>(p);
  rnn_kernel<<<dim3(NBLK), dim3(NTHR), 0, stream>>>(p);
  out_gemm<<<dim3(2048), dim3(512), 0, stream>>>(p.bout, p.out);
}